// Round 6
// baseline (180593.005 us; speedup 1.0000x reference)
//
#include <hip/hip_runtime.h>

#define BB 32
#define TT 256
#define SS 1600
#define DE 1024
#define VV 1000
#define EM 512
#define PR 256
#define LU 1024
#define AA 128
#define FF 32
#define KK 31

typedef __attribute__((ext_vector_type(8))) short short8;
typedef __attribute__((ext_vector_type(4))) float f32x4;

__device__ __forceinline__ float bf2f(ushort u) {
  unsigned int x = ((unsigned int)u) << 16;
  return __builtin_bit_cast(float, x);
}
__device__ __forceinline__ ushort f2bf(float f) {
  unsigned int x = __builtin_bit_cast(unsigned int, f);
  return (ushort)((x + 0x7FFFu + ((x >> 16) & 1u)) >> 16);
}
__device__ __forceinline__ void gload16(const void* g, void* l) {
  __builtin_amdgcn_global_load_lds(
      (const __attribute__((address_space(1))) void*)g,
      (__attribute__((address_space(3))) void*)l, 16, 0, 0);
}
__device__ __forceinline__ float ftanh(float x) {
  float e = __expf(2.f * x);
  return 1.f - 2.f / (e + 1.f);
}
__device__ __forceinline__ float fsig(float x) {
  return 1.f / (1.f + __expf(-x));
}

// ---------------- once-per-call precompute ----------------

__global__ __launch_bounds__(256) void conv_mem(const float* __restrict__ in,
                                                ushort* __restrict__ out, int n4)
{
  int i = blockIdx.x * 256 + threadIdx.x;
  if (i < n4) {
    float4 v = *(const float4*)(in + (size_t)i * 4);
    ushort4 o;
    o.x = f2bf(v.x); o.y = f2bf(v.y); o.z = f2bf(v.z); o.w = f2bf(v.w);
    *(ushort4*)(out + (size_t)i * 4) = o;
  }
}

__global__ __launch_bounds__(256) void pack_wu(const float* __restrict__ Wm,
    const float* __restrict__ Um, int lenW, int ktot, ushort* __restrict__ out, int nS)
{
  int bid = blockIdx.x;
  int kg = bid & 3, S = (bid >> 2) % nS, jb = (bid >> 2) / nS;
  int t = threadIdx.x;
  int c = t >> 1, e4 = (t & 1) * 4;
  int kbase = S * 32 + kg * 8 + e4;
  int j = jb * 128 + c;
  ushort* op = out + ((size_t)(jb * nS + S) * 4 + kg) * 1024 + c * 8 + e4;
#pragma unroll
  for (int i = 0; i < 4; i++) {
    int k = kbase + i;
    float v = 0.f;
    if (k < lenW)      v = Wm[(size_t)k * 4096 + j];
    else if (k < ktot) v = Um[(size_t)(k - lenW) * 4096 + j];
    op[i] = f2bf(v);
  }
}

__global__ __launch_bounds__(256) void keys_kernel(const float* __restrict__ mem,
                                                   const float* __restrict__ Wmem,
                                                   float* __restrict__ keys)
{
  int stile = blockIdx.x;
  int b = blockIdx.y;
  int t = threadIdx.x;
  __shared__ float Xt[8 * 1032];
  const float* mp = mem + ((size_t)b * SS + (size_t)stile * 8) * DE;
  for (int li = t; li < 8 * 256; li += 256) {
    int row = li >> 8, c4 = li & 255;
    float4 v = *(const float4*)(mp + row * DE + c4 * 4);
    *(float4*)(Xt + row * 1032 + c4 * 4) = v;
  }
  __syncthreads();
  int sl = t >> 5, u = t & 31;
  float acc[4] = {0.f, 0.f, 0.f, 0.f};
  for (int k = 0; k < DE; k++) {
    float x = Xt[sl * 1032 + k];
    const float* wr = Wmem + k * AA;
#pragma unroll
    for (int jj = 0; jj < 4; jj++) acc[jj] += x * wr[u + 32 * jj];
  }
  float* kp = keys + ((size_t)b * SS + (size_t)stile * 8 + sl) * AA;
#pragma unroll
  for (int jj = 0; jj < 4; jj++) kp[u + 32 * jj] = acc[jj];
}

__global__ void mconv_kernel(const float* __restrict__ ck, const float* __restrict__ Wloc,
                             float* __restrict__ M)
{
  int a = threadIdx.x;
  int k = blockIdx.x;
  float acc = 0.f;
  for (int c = 0; c < FF; c++) acc += ck[k * FF + c] * Wloc[c * AA + a];
  M[k * AA + a] = acc;
}

__global__ __launch_bounds__(256) void prenet_all(const int* __restrict__ tokens,
    const float* __restrict__ emb, const float* __restrict__ Wp1, const float* __restrict__ bp1,
    const float* __restrict__ Wp2, const float* __restrict__ bp2, float* __restrict__ P)
{
  int tstep = blockIdx.x;
  int bh = blockIdx.y;
  int t = threadIdx.x;
  __shared__ float X[16 * 512];
  __shared__ float P1[16 * 256];
  for (int li = t; li < 16 * 128; li += 256) {
    int bb = li >> 7, c4 = li & 127;
    int tok = tokens[(bh * 16 + bb) * TT + tstep];
    *(float4*)(X + bb * 512 + c4 * 4) = *(const float4*)(emb + (size_t)tok * EM + c4 * 4);
  }
  __syncthreads();
  int j = t;
  float acc[16];
#pragma unroll
  for (int i = 0; i < 16; i++) acc[i] = 0.f;
  for (int k = 0; k < EM; k++) {
    float w = Wp1[k * PR + j];
#pragma unroll
    for (int i = 0; i < 16; i++) acc[i] += X[i * 512 + k] * w;
  }
#pragma unroll
  for (int i = 0; i < 16; i++) P1[i * 256 + j] = fmaxf(acc[i] + bp1[j], 0.f);
  __syncthreads();
#pragma unroll
  for (int i = 0; i < 16; i++) acc[i] = 0.f;
  for (int k = 0; k < PR; k++) {
    float w = Wp2[k * PR + j];
#pragma unroll
    for (int i = 0; i < 16; i++) acc[i] += P1[i * 256 + k] * w;
  }
  float* outp = P + (size_t)tstep * BB * PR + (size_t)bh * 16 * PR;
#pragma unroll
  for (int i = 0; i < 16; i++) outp[i * PR + j] = fmaxf(acc[i] + bp2[j], 0.f);
}

// ---------------- grid barrier (tree: 32 counters + sense) ----------------
__device__ __forceinline__ void gbar(int* cnt, int* sense, int ep)
{
  __syncthreads();
  if (threadIdx.x == 0) {
    __threadfence();
    __hip_atomic_fetch_add(&cnt[blockIdx.x & 31], 1, __ATOMIC_RELEASE,
                           __HIP_MEMORY_SCOPE_AGENT);
  }
  if (blockIdx.x == 0) {
    if (threadIdx.x < 32) {
      int target = 8 * ep;   // 256 blocks / 32 groups
      while (__hip_atomic_load(&cnt[threadIdx.x], __ATOMIC_ACQUIRE,
                               __HIP_MEMORY_SCOPE_AGENT) < target)
        __builtin_amdgcn_s_sleep(1);
    }
    __syncthreads();
    if (threadIdx.x == 0)
      __hip_atomic_store(sense, ep, __ATOMIC_RELEASE, __HIP_MEMORY_SCOPE_AGENT);
  } else {
    if (threadIdx.x == 0) {
      while (__hip_atomic_load(sense, __ATOMIC_ACQUIRE,
                               __HIP_MEMORY_SCOPE_AGENT) < ep)
        __builtin_amdgcn_s_sleep(1);
    }
  }
  if (threadIdx.x == 0) __threadfence();
  __syncthreads();
}

// ---------------- phase: MFMA bf16 batched GEMM ----------------
__device__ void gemm_phase(int bid,
    const float* x0, int len0, const float* x1, int len1, const float* x2, int len2,
    const ushort* WUP, int nS, int chunk, float* zp, char* ldsbuf)
{
  ushort* wlT = (ushort*)ldsbuf;              // 3 * 8192
  ushort* xl  = (ushort*)(ldsbuf + 49152);    // 32 * (chunk+8)
  const int jb = bid >> 3, kc = bid & 7;
  const int t = threadIdx.x;
  const int lane = t & 63;
  const int wv = __builtin_amdgcn_readfirstlane(t >> 6);
  const int PADK = chunk + 8;
  const int nst = chunk >> 6;
  const int k0 = kc * chunk;
  const int S0 = k0 >> 5;
  const size_t jbS = (size_t)jb * nS;
  const int lenW01 = len0 + len1;
  const int ktot = lenW01 + len2;

  auto stage = [&](int s) {
    int buf = s % 3;
    int Sb = S0 + s * 2;
#pragma unroll
    for (int sub = 0; sub < 4; sub++) {
      int inst = wv * 4 + sub;
      const ushort* src = WUP + (jbS + Sb + (inst >> 3)) * 4096
                        + (size_t)(((inst & 7) * 64 + lane) * 8);
      ushort* dst = wlT + buf * 8192 + inst * 512;
      gload16(src, dst);
    }
  };

  stage(0);
  stage(1);

  for (int b = 0; b < 32; b++) {
    for (int kk = t; kk < chunk; kk += 256) {
      int k = k0 + kk;
      float val = 0.f;
      if (k < ktot) {
        const float* xp; int str; int off;
        if (k < len0)        { xp = x0; str = len0; off = k; }
        else if (k < lenW01) { xp = x1; str = len1; off = k - len0; }
        else                 { xp = x2; str = len2; off = k - lenW01; }
        val = xp[(size_t)b * str + off];
      }
      xl[b * PADK + kk] = f2bf(val);
    }
  }
  __syncthreads();   // drains all vmcnt -> counted waits below exact

  f32x4 acc[2][2];
#pragma unroll
  for (int mt = 0; mt < 2; mt++)
#pragma unroll
    for (int nt = 0; nt < 2; nt++)
#pragma unroll
      for (int r = 0; r < 4; r++) acc[mt][nt][r] = 0.f;

  const int lane15 = lane & 15, kg = lane >> 4;

  for (int s = 0; s < nst; s++) {
    if (s + 2 < nst) stage(s + 2);
    int ahead = nst - 1 - s; if (ahead > 2) ahead = 2;
    if (ahead == 2)      asm volatile("s_waitcnt vmcnt(8)");
    else if (ahead == 1) asm volatile("s_waitcnt vmcnt(4)");
    else                 asm volatile("s_waitcnt vmcnt(0)");
    __builtin_amdgcn_s_barrier();
    __builtin_amdgcn_sched_barrier(0);
    const ushort* bb = wlT + (s % 3) * 8192 + kg * 1024 + (wv * 32 + lane15) * 8;
    const ushort* ab = xl + lane15 * PADK + s * 64 + kg * 8;
#pragma unroll
    for (int kh = 0; kh < 2; kh++) {
      short8 b0 = *(const short8*)(bb + kh * 4096);
      short8 b1 = *(const short8*)(bb + kh * 4096 + 128);
      short8 a0 = *(const short8*)(ab + kh * 32);
      short8 a1 = *(const short8*)(ab + kh * 32 + 16 * PADK);
      acc[0][0] = __builtin_amdgcn_mfma_f32_16x16x32_bf16(a0, b0, acc[0][0], 0, 0, 0);
      acc[0][1] = __builtin_amdgcn_mfma_f32_16x16x32_bf16(a0, b1, acc[0][1], 0, 0, 0);
      acc[1][0] = __builtin_amdgcn_mfma_f32_16x16x32_bf16(a1, b0, acc[1][0], 0, 0, 0);
      acc[1][1] = __builtin_amdgcn_mfma_f32_16x16x32_bf16(a1, b1, acc[1][1], 0, 0, 0);
    }
    asm volatile("s_waitcnt lgkmcnt(0)");
    __builtin_amdgcn_sched_barrier(0);
    __builtin_amdgcn_s_barrier();
  }

  int colb = jb * 128 + wv * 32 + lane15;
  int rowb = kg * 4;
#pragma unroll
  for (int mt = 0; mt < 2; mt++)
#pragma unroll
    for (int nt = 0; nt < 2; nt++)
#pragma unroll
      for (int r = 0; r < 4; r++) {
        int b = mt * 16 + rowb + r;
        zp[((size_t)kc * BB + b) * 4096 + colb + nt * 16] = acc[mt][nt][r];
      }
}

// ---------------- phase: LSTM finish (+pq partial / +stp h-dot partial) ----------------
__device__ void finish_phase(int bid, const float* zp, const float* bias,
    float* h, float* c, const float* Wq, float* pqp,
    const float* Ws, float* hpart, char* ldsbuf)
{
  float* gbuf = (float*)ldsbuf;        // 512
  float* hsh  = gbuf + 512;            // 128
  float* sh2  = hsh + 128;             // 256
  int b = bid >> 3, jq = bid & 7;
  int t = threadIdx.x;
  int g4 = t >> 6, jl = t & 63;
  int col0 = g4 * 1024 + jq * 128 + jl;
  float z0 = bias[col0], z1 = bias[col0 + 64];
#pragma unroll
  for (int kc = 0; kc < 8; kc++) {
    const float* zpt = zp + ((size_t)kc * BB + b) * 4096;
    z0 += zpt[col0]; z1 += zpt[col0 + 64];
  }
  gbuf[g4 * 128 + jl] = z0;
  gbuf[g4 * 128 + jl + 64] = z1;
  __syncthreads();
  if (t < 128) {
    int j = jq * 128 + t;
    float zi = gbuf[t], zf = gbuf[128 + t], zg = gbuf[256 + t], zo = gbuf[384 + t];
    float cn = fsig(zf) * c[b * LU + j] + fsig(zi) * ftanh(zg);
    float hn = fsig(zo) * ftanh(cn);
    c[b * LU + j] = cn;
    h[b * LU + j] = hn;
    hsh[t] = hn;
  }
  __syncthreads();
  if (pqp) {
    int a = t & 127, half = t >> 7;
    float acc = 0.f;
    const float* wq = Wq + (size_t)(jq * 128 + half * 64) * AA + a;
#pragma unroll 4
    for (int r = 0; r < 64; r++) acc += hsh[half * 64 + r] * wq[(size_t)r * AA];
    sh2[t] = acc;
    __syncthreads();
    if (t < 128) pqp[((size_t)jq * BB + b) * AA + t] = sh2[t] + sh2[t + 128];
  }
  if (hpart) {
    float v = (t < 128) ? hsh[t] * Ws[jq * 128 + t] : 0.f;
#pragma unroll
    for (int m = 1; m < 64; m <<= 1) v += __shfl_xor(v, m);
    if ((t & 63) == 0) sh2[t >> 6] = v;
    __syncthreads();
    if (t == 0) hpart[b * 8 + jq] = sh2[0] + sh2[1] + sh2[2] + sh2[3];
  }
}

// ---------------- phase: energy ----------------
__device__ void energy_phase(int bid, const float* keys, const float* pqp,
    const float* M, const float* ast, const float* Wv, const float* bv,
    const int* mlen, float* e, char* ldsbuf)
{
  float* astT = (float*)ldsbuf;            // 368
  float* Ml4  = astT + 368;                // 31*132
  float* wvp  = Ml4 + 31 * 132;            // 256
  int t = threadIdx.x;
  for (int w = bid; w < 13 * 32; w += 256) {
    int tile = w >> 5, b = w & 31;
    int s0 = tile * 128, ml = mlen[b];
    if (s0 < ml) {
      for (int idx = t; idx < 368; idx += 256) {
        int G = idx >> 3, i = idx & 7;
        int s = s0 + G - 15 + 16 * i;
        astT[idx] = (s >= 0 && s < SS) ? ast[b * SS + s] : 0.f;
      }
      for (int idx = t; idx < KK * AA; idx += 256) {
        int k = idx >> 7, a = idx & 127;
        Ml4[k * 132 + a] = M[idx];
      }
      if (t < 128) wvp[t] = Wv[t];
      else {
        int a = t - 128;
        float s = 0.f;
#pragma unroll
        for (int jq = 0; jq < 8; jq++) s += pqp[((size_t)jq * BB + b) * AA + a];
        wvp[128 + a] = s;
      }
      __syncthreads();
      int u = t & 15, g = t >> 4;
      int a0 = u * 8;
      float4 wv0 = *(float4*)&wvp[a0], wv1 = *(float4*)&wvp[a0 + 4];
      float4 pq0 = *(float4*)&wvp[128 + a0], pq1 = *(float4*)&wvp[128 + a0 + 4];
      float arg[8][8];
#pragma unroll
      for (int i = 0; i < 8; i++) {
        int s = s0 + g + 16 * i;
        if (s < SS) {
          const float* kp = keys + ((size_t)b * SS + s) * AA + a0;
          float4 k0 = *(const float4*)kp, k1 = *(const float4*)(kp + 4);
          arg[i][0] = k0.x + pq0.x; arg[i][1] = k0.y + pq0.y;
          arg[i][2] = k0.z + pq0.z; arg[i][3] = k0.w + pq0.w;
          arg[i][4] = k1.x + pq1.x; arg[i][5] = k1.y + pq1.y;
          arg[i][6] = k1.z + pq1.z; arg[i][7] = k1.w + pq1.w;
        } else {
#pragma unroll
          for (int jj = 0; jj < 8; jj++) arg[i][jj] = 0.f;
        }
      }
      for (int k = 0; k < KK; k++) {
        float4 m0 = *(float4*)&Ml4[k * 132 + a0];
        float4 m1 = *(float4*)&Ml4[k * 132 + a0 + 4];
        float4 as0 = *(float4*)&astT[(g + k) * 8];
        float4 as1 = *(float4*)&astT[(g + k) * 8 + 4];
        float asv[8] = {as0.x, as0.y, as0.z, as0.w, as1.x, as1.y, as1.z, as1.w};
#pragma unroll
        for (int i = 0; i < 8; i++) {
          float aw = asv[i];
          arg[i][0] += aw * m0.x; arg[i][1] += aw * m0.y;
          arg[i][2] += aw * m0.z; arg[i][3] += aw * m0.w;
          arg[i][4] += aw * m1.x; arg[i][5] += aw * m1.y;
          arg[i][6] += aw * m1.z; arg[i][7] += aw * m1.w;
        }
      }
      float bvv = bv[0];
#pragma unroll
      for (int i = 0; i < 8; i++) {
        int s = s0 + g + 16 * i;
        float v = ftanh(arg[i][0]) * wv0.x + ftanh(arg[i][1]) * wv0.y
                + ftanh(arg[i][2]) * wv0.z + ftanh(arg[i][3]) * wv0.w
                + ftanh(arg[i][4]) * wv1.x + ftanh(arg[i][5]) * wv1.y
                + ftanh(arg[i][6]) * wv1.z + ftanh(arg[i][7]) * wv1.w;
#pragma unroll
        for (int m = 1; m < 16; m <<= 1) v += __shfl_xor(v, m);
        if (u == 0 && s < SS) e[b * SS + s] = (s < ml) ? (v + bvv) : -1e9f;
      }
    }
    __syncthreads();
  }
}

// ---------------- phase: softmax + ast + ctx partials ----------------
__device__ void ctxsm_phase(int bid, const float* e, const int* mlen,
    const ushort* mem_bf, float* ast, float* cp, char* ldsbuf)
{
  float* red  = (float*)ldsbuf;       // 8
  float* alsh = red + 8;              // 200
  int sc = bid >> 5, b = bid & 31;
  int t = threadIdx.x;
  int ml = mlen[b];
  int s0 = sc * 200;
  int cnt = ml - s0; if (cnt > 200) cnt = 200;
  if (cnt <= 0) {
    float4 z = make_float4(0.f, 0.f, 0.f, 0.f);
    *(float4*)&cp[((size_t)sc * BB + b) * DE + t * 4] = z;
    return;
  }
  const float* er = e + b * SS;
  float m = -3e38f;
  for (int s = t; s < ml; s += 256) m = fmaxf(m, er[s]);
#pragma unroll
  for (int msk = 1; msk < 64; msk <<= 1) m = fmaxf(m, __shfl_xor(m, msk));
  if ((t & 63) == 0) red[t >> 6] = m;
  __syncthreads();
  m = fmaxf(fmaxf(red[0], red[1]), fmaxf(red[2], red[3]));
  __syncthreads();
  float sum = 0.f;
  for (int s = t; s < ml; s += 256) sum += __expf(er[s] - m);
#pragma unroll
  for (int msk = 1; msk < 64; msk <<= 1) sum += __shfl_xor(sum, msk);
  if ((t & 63) == 0) red[t >> 6] = sum;
  __syncthreads();
  float inv = 1.f / (red[0] + red[1] + red[2] + red[3]);
  if (t < cnt) {
    float a_ = __expf(er[s0 + t] - m) * inv;
    alsh[t] = a_;
    ast[b * SS + s0 + t] += a_;
  }
  __syncthreads();
  float4 acc = make_float4(0.f, 0.f, 0.f, 0.f);
  const ushort* mp = mem_bf + ((size_t)b * SS + s0) * DE + t * 4;
#pragma unroll 8
  for (int i = 0; i < cnt; i++) {
    uint2 v = *(const uint2*)(mp + (size_t)i * DE);
    float a_ = alsh[i];
    acc.x += a_ * bf2f((ushort)(v.x & 0xffff));
    acc.y += a_ * bf2f((ushort)(v.x >> 16));
    acc.z += a_ * bf2f((ushort)(v.y & 0xffff));
    acc.w += a_ * bf2f((ushort)(v.y >> 16));
  }
  *(float4*)&cp[((size_t)sc * BB + b) * DE + t * 4] = acc;
}

// ---------------- phase: ctx reduce ----------------
__device__ void ctxred_phase(int bid, const float* cp, float* ctx)
{
  int b = bid >> 3, dq = bid & 7;
  int t = threadIdx.x;
  if (t < 128) {
    int d = dq * 128 + t;
    float s = 0.f;
#pragma unroll
    for (int sc = 0; sc < 8; sc++) s += cp[((size_t)sc * BB + b) * DE + d];
    ctx[b * DE + d] = s;
  }
}

// ---------------- phase: fp32 cls GEMV (jb4 x kc32, chunk 64) ----------------
__device__ void gemvJ_phase(int bid, const float* x0, const float* x1,
    const float* Wmat, float* zp, char* ldsbuf)
{
  if (bid >= 128) return;
  float* wl = (float*)ldsbuf;          // 2*16*256 = 8192 floats
  float* xl = wl + 8192;               // 32*64
  int jb = bid >> 5, kc = bid & 31;
  int t = threadIdx.x;
  int lane = t & 63;
  int wv = __builtin_amdgcn_readfirstlane(t >> 6);
  int k0 = kc * 64;
  int colbase = jb * 256 + lane * 4;
  bool jok = (colbase + 4 <= VV);

  for (int idx = t; idx < 2048; idx += 256) {
    int b = idx >> 6, kk = idx & 63;
    int k = k0 + kk;
    xl[b * 64 + kk] = (k < LU) ? x0[(size_t)b * LU + k] : x1[(size_t)b * LU + (k - LU)];
  }
  __syncthreads();

  auto stage = [&](int s) {
    int buf = s & 1;
    int rbase = k0 + s * 16 + wv * 4;
#pragma unroll
    for (int rr = 0; rr < 4; rr++) {
      int r = rbase + rr;
      const float* src = Wmat + (size_t)r * VV + colbase;
      float* dst = &wl[(buf * 16 + wv * 4 + rr) * 256];
      if (jok) gload16(src, dst);
    }
  };

  stage(0);
  float acc[8][4];
#pragma unroll
  for (int bi = 0; bi < 8; bi++)
    for (int cc = 0; cc < 4; cc++) acc[bi][cc] = 0.f;

  for (int s = 0; s < 4; s++) {
    if (s + 1 < 4) { stage(s + 1); asm volatile("s_waitcnt vmcnt(4)"); }
    else           { asm volatile("s_waitcnt vmcnt(0)"); }
    __builtin_amdgcn_s_barrier();
    __builtin_amdgcn_sched_barrier(0);
    const float* wb = &wl[(s & 1) * 16 * 256];
    int xoff = s * 16;
#pragma unroll
    for (int k4 = 0; k4 < 4; k4++) {
      float4 xv[8];
#pragma unroll
      for (int bi = 0; bi < 8; bi++)
        xv[bi] = *(const float4*)&xl[(wv * 8 + bi) * 64 + xoff + k4 * 4];
#pragma unroll
      for (int kk = 0; kk < 4; kk++) {
        float4 w = *(const float4*)&wb[(k4 * 4 + kk) * 256 + lane * 4];
#pragma unroll
        for (int bi = 0; bi < 8; bi++) {
          float xs = (&xv[bi].x)[kk];
          acc[bi][0] += xs * w.x; acc[bi][1] += xs * w.y;
          acc[bi][2] += xs * w.z; acc[bi][3] += xs * w.w;
        }
      }
    }
    asm volatile("s_waitcnt lgkmcnt(0)");
    __builtin_amdgcn_sched_barrier(0);
    __builtin_amdgcn_s_barrier();
  }

  if (jok) {
#pragma unroll
    for (int bi = 0; bi < 8; bi++) {
      int b = wv * 8 + bi;
      *(float4*)&zp[((size_t)kc * BB + b) * VV + colbase] =
          make_float4(acc[bi][0], acc[bi][1], acc[bi][2], acc[bi][3]);
    }
  }
}

// ---------------- phase: cls write + stp partial ----------------
__device__ void cls_phase(int bid, const float* zp, const float* bc,
    const float* Ws, float* out, int ts, float* spart, char* ldsbuf)
{
  float* red = (float*)ldsbuf;
  int b = bid >> 3, vq = bid & 7;
  int t = threadIdx.x;
  float sacc = 0.f;
  if (t < 128) {
    int v = vq * 128 + t;
    if (v < VV) {
      float acc = bc[v];
#pragma unroll
      for (int kc = 0; kc < 32; kc++) acc += zp[((size_t)kc * BB + b) * VV + v];
      out[(size_t)b * TT * VV + (size_t)ts * VV + v] = acc;
      sacc = acc * Ws[LU + v];
    }
  }
#pragma unroll
  for (int m = 1; m < 64; m <<= 1) sacc += __shfl_xor(sacc, m);
  if ((t & 63) == 0) red[t >> 6] = sacc;
  __syncthreads();
  if (t == 0) spart[b * 8 + vq] = red[0] + red[1] + red[2] + red[3];
}

// ---------------- persistent step-loop kernel ----------------
__global__ __launch_bounds__(256, 2) void step_loop(
    const float* P_all, float* ctx, float* h_a, float* c_a, float* h0, float* c0,
    float* h1, float* c1, float* ast, float* pqp, float* ebuf, float* zp, float* cp,
    const float* keys, const float* M, const ushort* mem_bf,
    const ushort* WUPa, const ushort* WUP0, const ushort* WUP1,
    const float* Wq, const float* Wv, const float* bv, const int* mlen,
    const float* ba, const float* b0, const float* b1,
    const float* Wc, const float* bc, const float* Ws,
    float* out, float* spart, float* hpart, int* bar)
{
  __shared__ alignas(16) char ldsbuf[74240];
  int bid = blockIdx.x;
  int* cnt = bar;
  int* sense = bar + 32;
  int ep = 0;
#pragma unroll 1
  for (int ts = 0; ts < TT; ts++) {
    gemm_phase(bid, P_all + (size_t)ts * BB * PR, PR, ctx, DE, h_a, LU,
               WUPa, 80, 320, zp, ldsbuf);
    gbar(cnt, sense, ++ep);
    finish_phase(bid, zp, ba, h_a, c_a, Wq, pqp, nullptr, nullptr, ldsbuf);
    gbar(cnt, sense, ++ep);
    energy_phase(bid, keys, pqp, M, ast, Wv, bv, mlen, ebuf, ldsbuf);
    gbar(cnt, sense, ++ep);
    ctxsm_phase(bid, ebuf, mlen, mem_bf, ast, cp, ldsbuf);
    gbar(cnt, sense, ++ep);
    ctxred_phase(bid, cp, ctx);
    gbar(cnt, sense, ++ep);
    gemm_phase(bid, h_a, LU, ctx, DE, h0, LU, WUP0, 96, 384, zp, ldsbuf);
    gbar(cnt, sense, ++ep);
    finish_phase(bid, zp, b0, h0, c0, nullptr, nullptr, nullptr, nullptr, ldsbuf);
    gbar(cnt, sense, ++ep);
    gemm_phase(bid, h0, LU, h1, LU, h0, 0, WUP1, 64, 256, zp, ldsbuf);
    gbar(cnt, sense, ++ep);
    finish_phase(bid, zp, b1, h1, c1, nullptr, nullptr, Ws, hpart + ts * 256, ldsbuf);
    gbar(cnt, sense, ++ep);
    gemvJ_phase(bid, h1, ctx, Wc, zp, ldsbuf);
    gbar(cnt, sense, ++ep);
    cls_phase(bid, zp, bc, Ws, out, ts, spart + ts * 256, ldsbuf);
    gbar(cnt, sense, ++ep);
  }
}

// ---------------- stp finalize ----------------
__global__ __launch_bounds__(256) void final_stp(const float* __restrict__ spart,
    const float* __restrict__ hpart, const float* __restrict__ bs, float* __restrict__ out)
{
  int idx = blockIdx.x * 256 + threadIdx.x;
  if (idx < TT * BB) {
    int ts = idx >> 5, b = idx & 31;
    float s = bs[0];
#pragma unroll
    for (int i = 0; i < 8; i++)
      s += spart[ts * 256 + b * 8 + i] + hpart[ts * 256 + b * 8 + i];
    out[(size_t)BB * TT * VV + (size_t)b * TT + ts] = s;
  }
}

// ---------------- launcher ----------------

extern "C" void kernel_launch(void* const* d_in, const int* in_sizes, int n_in,
                              void* d_out, int out_size, void* d_ws, size_t ws_size,
                              hipStream_t stream)
{
  const int*   tokens = (const int*)  d_in[0];
  const float* memory = (const float*)d_in[1];
  const int*   mlen   = (const int*)  d_in[2];
  const float* emb    = (const float*)d_in[3];
  const float* Wp1    = (const float*)d_in[4];
  const float* bp1    = (const float*)d_in[5];
  const float* Wp2    = (const float*)d_in[6];
  const float* bp2    = (const float*)d_in[7];
  const float* Wq     = (const float*)d_in[8];
  const float* Wmem   = (const float*)d_in[9];
  const float* convk  = (const float*)d_in[10];
  const float* Wloc   = (const float*)d_in[11];
  const float* Wv     = (const float*)d_in[12];
  const float* bv     = (const float*)d_in[13];
  const float* Wa     = (const float*)d_in[14];
  const float* Ua     = (const float*)d_in[15];
  const float* ba     = (const float*)d_in[16];
  const float* W0     = (const float*)d_in[17];
  const float* U0     = (const float*)d_in[18];
  const float* b0     = (const float*)d_in[19];
  const float* W1     = (const float*)d_in[20];
  const float* U1     = (const float*)d_in[21];
  const float* b1     = (const float*)d_in[22];
  const float* Wc     = (const float*)d_in[23];
  const float* bc     = (const float*)d_in[24];
  const float* Ws     = (const float*)d_in[25];
  const float* bs     = (const float*)d_in[26];
  float* out = (float*)d_out;
  float* ws = (float*)d_ws;

  size_t o = 0;
  float* keys  = ws + o;  o += (size_t)BB * SS * AA;
  float* M     = ws + o;  o += 4096;
  float* P_all = ws + o;  o += (size_t)TT * BB * PR;
  float* st    = ws + o;
  float* h_a = st;
  float* c_a = h_a + BB * LU;
  float* h0  = c_a + BB * LU;
  float* c0  = h0 + BB * LU;
  float* h1  = c0 + BB * LU;
  float* c1  = h1 + BB * LU;
  float* ctx = c1 + BB * LU;
  float* ast = ctx + BB * DE;
  size_t stcount = (size_t)6 * BB * LU + (size_t)BB * DE + (size_t)BB * SS;
  o += stcount;
  float* pqp   = ws + o;  o += (size_t)8 * BB * AA;
  float* ebuf  = ws + o;  o += (size_t)BB * SS;
  float* zp    = ws + o;  o += (size_t)8 * BB * 4096;
  float* cp    = ws + o;  o += (size_t)8 * BB * DE;
  float* spart = ws + o;  o += (size_t)TT * BB * 8;
  float* hpart = ws + o;  o += (size_t)TT * BB * 8;
  int*   bar   = (int*)(ws + o);  o += 64;
  ushort* mem_bf = (ushort*)(ws + o);  o += (size_t)BB * SS * DE / 2;
  ushort* WUPa   = (ushort*)(ws + o);  o += (size_t)2560 * 4096 / 2;
  ushort* WUP0   = (ushort*)(ws + o);  o += (size_t)3072 * 4096 / 2;
  ushort* WUP1   = (ushort*)(ws + o);  o += (size_t)2048 * 4096 / 2;

  hipMemsetAsync(st, 0, stcount * sizeof(float), stream);
  hipMemsetAsync(bar, 0, 64 * sizeof(int), stream);
  conv_mem<<<(BB * SS * DE / 4 + 255) / 256, 256, 0, stream>>>(memory, mem_bf,
                                                               BB * SS * DE / 4);
  pack_wu<<<32 * 80 * 4, 256, 0, stream>>>(Wa, Ua, PR + DE, 2304, WUPa, 80);
  pack_wu<<<32 * 96 * 4, 256, 0, stream>>>(W0, U0, LU + DE, 3072, WUP0, 96);
  pack_wu<<<32 * 64 * 4, 256, 0, stream>>>(W1, U1, LU,      2048, WUP1, 64);
  keys_kernel<<<dim3(200, BB), 256, 0, stream>>>(memory, Wmem, keys);
  mconv_kernel<<<KK, AA, 0, stream>>>(convk, Wloc, M);
  prenet_all<<<dim3(TT, 2), 256, 0, stream>>>(tokens, emb, Wp1, bp1, Wp2, bp2, P_all);

  step_loop<<<256, 256, 0, stream>>>(
      P_all, ctx, h_a, c_a, h0, c0, h1, c1, ast, pqp, ebuf, zp, cp,
      keys, M, mem_bf, WUPa, WUP0, WUP1,
      Wq, Wv, bv, mlen, ba, b0, b1, Wc, bc, Ws,
      out, spart, hpart, bar);

  final_stp<<<32, 256, 0, stream>>>(spart, hpart, bs, out);
}

// Round 7
// 106528.931 us; speedup vs baseline: 1.6952x; 1.6952x over previous
//
#include <hip/hip_runtime.h>

#define BB 32
#define TT 256
#define SS 1600
#define DE 1024
#define VV 1000
#define EM 512
#define PR 256
#define LU 1024
#define AA 128
#define FF 32
#define KK 31

typedef __attribute__((ext_vector_type(8))) short short8;
typedef __attribute__((ext_vector_type(4))) float f32x4;

// ---------- workspace layout (float units) ----------
#define F_KEYS   ((size_t)0)
#define F_M      (F_KEYS + 6553600)
#define F_PBF    (F_M + 4096)            // ushort TT*8192
#define F_WPA    (F_PBF + 1048576)       // ushort 256*5*8192
#define F_WP0    (F_WPA + 5242880)       // ushort 256*6*8192
#define F_WP1    (F_WP0 + 6291456)       // ushort 256*4*8192
#define F_WCP    (F_WP1 + 4194304)       // float 250*2048*4
#define F_MEMBF  (F_WCP + 2048000)       // ushort 32*1600*1024
#define F_ST     (F_MEMBF + 26214400)
#define F_HA32   (F_ST)
#define F_CA     (F_HA32 + 32768)
#define F_C0     (F_CA + 32768)
#define F_C1     (F_C0 + 32768)
#define F_AST    (F_C1 + 32768)          // 51200
#define F_HABF   (F_AST + 51200)         // ushort 2*32768
#define F_H0BF   (F_HABF + 32768)
#define F_H1BF   (F_H0BF + 32768)
#define F_CTXBF  (F_H1BF + 32768)        // ushort 32768
#define F_CTXT   (F_CTXBF + 16384)       // float 32768
#define F_H1T    (F_CTXT + 32768)        // float 32768
#define F_ZERO   (F_H1T + 32768)         // ushort 16384 (zero chunk)
#define F_BAR    (F_ZERO + 8192)
#define F_STEND  (F_BAR + 64)
#define F_HP     (F_STEND)               // float TT*32*256
#define F_SP     (F_HP + 2097152)        // float TT*32*256
#define F_E      (F_SP + 2097152)        // float 32*1600

__device__ __forceinline__ float bf2f(ushort u) {
  unsigned int x = ((unsigned int)u) << 16;
  return __builtin_bit_cast(float, x);
}
__device__ __forceinline__ ushort f2bf(float f) {
  unsigned int x = __builtin_bit_cast(unsigned int, f);
  return (ushort)((x + 0x7FFFu + ((x >> 16) & 1u)) >> 16);
}
__device__ __forceinline__ void gload16(const void* g, void* l) {
  __builtin_amdgcn_global_load_lds(
      (const __attribute__((address_space(1))) void*)g,
      (__attribute__((address_space(3))) void*)l, 16, 0, 0);
}
__device__ __forceinline__ float ftanh(float x) {
  float e = __expf(2.f * x);
  return 1.f - 2.f / (e + 1.f);
}
__device__ __forceinline__ float fsig(float x) {
  return 1.f / (1.f + __expf(-x));
}

// ---------------- once-per-call precompute ----------------

__global__ __launch_bounds__(256) void conv_mem(const float* __restrict__ in,
                                                ushort* __restrict__ out, int n4)
{
  int i = blockIdx.x * 256 + threadIdx.x;
  if (i < n4) {
    float4 v = *(const float4*)(in + (size_t)i * 4);
    ushort4 o;
    o.x = f2bf(v.x); o.y = f2bf(v.y); o.z = f2bf(v.z); o.w = f2bf(v.w);
    *(ushort4*)(out + (size_t)i * 4) = o;
  }
}

// pack LSTM layer weights: dst[blk][kc][Sl][c][kg^(c&3)][e], CK=512, bf16
__global__ __launch_bounds__(256) void pack_lstm(const float* __restrict__ Wm,
    const float* __restrict__ Um, int lenW, int ktot, ushort* __restrict__ dst, int kcmax)
{
  int k = blockIdx.x;
  int t = threadIdx.x;
  float vals[16];
  if (k < lenW) {
    const float* s = Wm + (size_t)k * 4096 + t * 16;
#pragma unroll
    for (int i = 0; i < 16; i++) vals[i] = s[i];
  } else if (k < ktot) {
    const float* s = Um + (size_t)(k - lenW) * 4096 + t * 16;
#pragma unroll
    for (int i = 0; i < 16; i++) vals[i] = s[i];
  } else {
#pragma unroll
    for (int i = 0; i < 16; i++) vals[i] = 0.f;
  }
  int kc = k >> 9, Sl = (k >> 5) & 15, kg = (k >> 3) & 3, e = k & 7;
#pragma unroll
  for (int i = 0; i < 16; i++) {
    int zcol = t * 16 + i;
    int gate = zcol >> 10, jj = zcol & 1023;
    int blk = jj >> 2, c = gate * 4 + (jj & 3);
    size_t off = ((size_t)blk * kcmax + kc) * 8192
               + Sl * 512 + c * 32 + ((kg ^ (c & 3)) * 8) + e;
    dst[off] = f2bf(vals[i]);
  }
}

// pack Wc: dst[cb][k][4] fp32
__global__ __launch_bounds__(256) void pack_wc(const float* __restrict__ Wc,
                                               float* __restrict__ dst)
{
  int k = blockIdx.x;  // 2048
  int t = threadIdx.x;
  if (t < 250) {
    float4 v = *(const float4*)(Wc + (size_t)k * VV + t * 4);
    *(float4*)(dst + (size_t)t * 8192 + k * 4) = v;
  }
}

__global__ __launch_bounds__(256) void keys_kernel(const float* __restrict__ mem,
                                                   const float* __restrict__ Wmem,
                                                   float* __restrict__ keys)
{
  int stile = blockIdx.x;
  int b = blockIdx.y;
  int t = threadIdx.x;
  __shared__ float Xt[8 * 1032];
  const float* mp = mem + ((size_t)b * SS + (size_t)stile * 8) * DE;
  for (int li = t; li < 8 * 256; li += 256) {
    int row = li >> 8, c4 = li & 255;
    float4 v = *(const float4*)(mp + row * DE + c4 * 4);
    *(float4*)(Xt + row * 1032 + c4 * 4) = v;
  }
  __syncthreads();
  int sl = t >> 5, u = t & 31;
  float acc[4] = {0.f, 0.f, 0.f, 0.f};
  for (int k = 0; k < DE; k++) {
    float x = Xt[sl * 1032 + k];
    const float* wr = Wmem + k * AA;
#pragma unroll
    for (int jj = 0; jj < 4; jj++) acc[jj] += x * wr[u + 32 * jj];
  }
  float* kp = keys + ((size_t)b * SS + (size_t)stile * 8 + sl) * AA;
#pragma unroll
  for (int jj = 0; jj < 4; jj++) kp[u + 32 * jj] = acc[jj];
}

__global__ void mconv_kernel(const float* __restrict__ ck, const float* __restrict__ Wloc,
                             float* __restrict__ M)
{
  int a = threadIdx.x;
  int k = blockIdx.x;
  float acc = 0.f;
  for (int c = 0; c < FF; c++) acc += ck[k * FF + c] * Wloc[c * AA + a];
  M[k * AA + a] = acc;
}

__global__ __launch_bounds__(256) void prenet_all(const int* __restrict__ tokens,
    const float* __restrict__ emb, const float* __restrict__ Wp1, const float* __restrict__ bp1,
    const float* __restrict__ Wp2, const float* __restrict__ bp2, ushort* __restrict__ Pbf)
{
  int tstep = blockIdx.x;
  int bh = blockIdx.y;
  int t = threadIdx.x;
  __shared__ float X[16 * 512];
  __shared__ float P1s[16 * 256];
  for (int li = t; li < 16 * 128; li += 256) {
    int bb = li >> 7, c4 = li & 127;
    int tok = tokens[(bh * 16 + bb) * TT + tstep];
    *(float4*)(X + bb * 512 + c4 * 4) = *(const float4*)(emb + (size_t)tok * EM + c4 * 4);
  }
  __syncthreads();
  int j = t;
  float acc[16];
#pragma unroll
  for (int i = 0; i < 16; i++) acc[i] = 0.f;
  for (int k = 0; k < EM; k++) {
    float w = Wp1[k * PR + j];
#pragma unroll
    for (int i = 0; i < 16; i++) acc[i] += X[i * 512 + k] * w;
  }
#pragma unroll
  for (int i = 0; i < 16; i++) P1s[i * 256 + j] = fmaxf(acc[i] + bp1[j], 0.f);
  __syncthreads();
#pragma unroll
  for (int i = 0; i < 16; i++) acc[i] = 0.f;
  for (int k = 0; k < PR; k++) {
    float w = Wp2[k * PR + j];
#pragma unroll
    for (int i = 0; i < 16; i++) acc[i] += P1s[i * 256 + k] * w;
  }
  ushort* outp = Pbf + (size_t)tstep * 8192 + (size_t)bh * 16 * 256;
#pragma unroll
  for (int i = 0; i < 16; i++) outp[i * 256 + j] = f2bf(fmaxf(acc[i] + bp2[j], 0.f));
}

// ---------------- grid barrier: relaxed spins, single fences ----------------
__device__ __forceinline__ void gbar(int* cnt, int* sense, int ep)
{
  __syncthreads();
  if (threadIdx.x == 0) {
    __threadfence();   // release once: drain + L2 writeback
    __hip_atomic_fetch_add(&cnt[blockIdx.x & 31], 1, __ATOMIC_RELAXED,
                           __HIP_MEMORY_SCOPE_AGENT);
  }
  if (blockIdx.x == 0) {
    if (threadIdx.x < 32) {
      int tgt = 8 * ep;
      while (__hip_atomic_load(&cnt[threadIdx.x], __ATOMIC_RELAXED,
                               __HIP_MEMORY_SCOPE_AGENT) < tgt)
        __builtin_amdgcn_s_sleep(4);
    }
    __syncthreads();
    if (threadIdx.x == 0)
      __hip_atomic_store(sense, ep, __ATOMIC_RELAXED, __HIP_MEMORY_SCOPE_AGENT);
  } else if (threadIdx.x == 0) {
    while (__hip_atomic_load(sense, __ATOMIC_RELAXED,
                             __HIP_MEMORY_SCOPE_AGENT) < ep)
      __builtin_amdgcn_s_sleep(4);
  }
  __syncthreads();
  if (threadIdx.x == 0) __threadfence();  // acquire once: invalidate L1/L2
  __syncthreads();
}

// ---------------- fused full-K gemm + gates ----------------
struct XSeg { const ushort* p0; int n0; const ushort* p1; int n1;
              const ushort* p2; int n2; const ushort* pz; };

__device__ __forceinline__ const ushort* xseg_ptr(const XSeg& xs, int hc)
{
  if (hc < xs.n0) return xs.p0 + (size_t)hc * 8192;
  hc -= xs.n0;
  if (hc < xs.n1) return xs.p1 + (size_t)hc * 8192;
  hc -= xs.n1;
  if (hc < xs.n2) return xs.p2 + (size_t)hc * 8192;
  return xs.pz;
}

__device__ void gemm_gates(int bid, const XSeg& xs, const ushort* Wp, int kcmax,
    const float* bias, float* cst, float* h32, ushort* hbf, float* hT,
    float* hpart_slot, const float* WsV, char* lds)
{
  ushort* wbuf = (ushort*)lds;                     // 2 * 8192 us
  ushort* xbuf = (ushort*)(lds + 32768);           // 2 * 16640 us
  float*  zsh  = (float*)(lds + 32768 + 66560);    // 2048 f
  const int t = threadIdx.x;
  const int lane = t & 63;
  const int w = __builtin_amdgcn_readfirstlane(t >> 6);
  const ushort* Wblk = Wp + (size_t)bid * kcmax * 8192;

  auto stage_w = [&](int kc, int buf) {
    const ushort* src = Wblk + (size_t)kc * 8192;
#pragma unroll
    for (int j = 0; j < 4; j++) {
      int Sl = w * 4 + j;
      gload16(src + Sl * 512 + lane * 8, wbuf + buf * 8192 + Sl * 512);
    }
  };
  auto stage_x = [&](int kc, int buf) {
#pragma unroll
    for (int h = 0; h < 2; h++) {
      const ushort* p = xseg_ptr(xs, kc * 2 + h);
#pragma unroll
      for (int i = 0; i < 4; i++) {
        int idx = i * 2048 + t * 8;
        int b = idx >> 8, ko = idx & 255;
        short8 v = *(const short8*)(p + idx);
        *(short8*)(xbuf + buf * 16640 + b * 520 + h * 256 + ko) = v;
      }
    }
  };

  stage_x(0, 0);
  stage_w(0, 0);

  f32x4 acc0 = {0.f, 0.f, 0.f, 0.f}, acc1 = {0.f, 0.f, 0.f, 0.f};
  const int c = lane & 15, kg = lane >> 4;
  const int wsw = c * 64 + ((kg ^ (c & 3)) * 16);   // byte off within Sl for B

#pragma unroll 1
  for (int kc = 0; kc < kcmax; kc++) {
    int cur = kc & 1;
    if (kc + 1 < kcmax) {
      stage_x(kc + 1, cur ^ 1);
      stage_w(kc + 1, cur ^ 1);
      asm volatile("s_waitcnt vmcnt(4) lgkmcnt(8)" ::: "memory");
    } else {
      asm volatile("s_waitcnt vmcnt(0) lgkmcnt(0)" ::: "memory");
    }
    __builtin_amdgcn_sched_barrier(0);
    __builtin_amdgcn_s_barrier();
    const char* wb = (const char*)(wbuf + cur * 8192);
    const char* xb = (const char*)(xbuf + cur * 16640);
#pragma unroll
    for (int j = 0; j < 4; j++) {
      int Sl = w * 4 + j;
      short8 bfr = *(const short8*)(wb + Sl * 1024 + wsw);
      short8 a0  = *(const short8*)(xb + c * 1040 + Sl * 64 + kg * 16);
      short8 a1  = *(const short8*)(xb + (c + 16) * 1040 + Sl * 64 + kg * 16);
      acc0 = __builtin_amdgcn_mfma_f32_16x16x32_bf16(a0, bfr, acc0, 0, 0, 0);
      acc1 = __builtin_amdgcn_mfma_f32_16x16x32_bf16(a1, bfr, acc1, 0, 0, 0);
    }
    asm volatile("s_waitcnt lgkmcnt(0)" ::: "memory");
    __builtin_amdgcn_sched_barrier(0);
    __builtin_amdgcn_s_barrier();
  }

#pragma unroll
  for (int r = 0; r < 4; r++) {
    zsh[(w * 32 + kg * 4 + r) * 16 + c] = acc0[r];
    zsh[(w * 32 + 16 + kg * 4 + r) * 16 + c] = acc1[r];
  }
  __syncthreads();
  if (t < 128) {
    int b = t >> 2, jl = t & 3;
    int j = bid * 4 + jl;
    float z[4];
#pragma unroll
    for (int g = 0; g < 4; g++) {
      float s = bias[g * 1024 + j];
#pragma unroll
      for (int ww = 0; ww < 4; ww++) s += zsh[(ww * 32 + b) * 16 + g * 4 + jl];
      z[g] = s;
    }
    float cn = fsig(z[1]) * cst[b * 1024 + j] + fsig(z[0]) * ftanh(z[2]);
    float hn = fsig(z[3]) * ftanh(cn);
    cst[b * 1024 + j] = cn;
    if (h32) h32[b * 1024 + j] = hn;
    hbf[(j >> 8) * 8192 + b * 256 + (j & 255)] = f2bf(hn);
    if (hT) hT[j * 32 + b] = hn;
    if (hpart_slot) {
      float v = hn * WsV[j];
      v += __shfl_xor(v, 1);
      v += __shfl_xor(v, 2);
      if (jl == 0) hpart_slot[b * 256 + bid] = v;
    }
  }
}

// ---------------- energy (pq inline) ----------------
__device__ void energy_phase(int bid, const float* keys, const float* ha32,
    const float* M, const float* ast, const float* Wq, const float* Wv,
    const float* bv, const int* mlen, float* e, char* lds)
{
  int b = bid >> 3, tq = bid & 7;
  int base = tq * 200;
  int ml = mlen[b];
  if (base >= ml) return;
  float* hsh  = (float*)lds;        // 1024
  float* Ml4  = hsh + 1024;         // 4092
  float* wvp  = Ml4 + 4092;         // 256
  float* pqsh = wvp + 256;          // 256
  float* astT = pqsh + 256;         // 368
  int t = threadIdx.x;
  *(float4*)(hsh + t * 4) = *(const float4*)(ha32 + b * 1024 + t * 4);
  for (int idx = t; idx < KK * AA; idx += 256) {
    int k = idx >> 7, a = idx & 127;
    Ml4[k * 132 + a] = M[idx];
  }
  if (t < 128) wvp[t] = Wv[t];
  __syncthreads();
  {
    int a = t & 127, half = t >> 7;
    float acc = 0.f;
    const float* wq = Wq + (size_t)(half * 512) * AA + a;
    const float* hh = hsh + half * 512;
#pragma unroll 8
    for (int kk = 0; kk < 512; kk++) acc += hh[kk] * wq[(size_t)kk * AA];
    pqsh[t] = acc;
  }
  __syncthreads();
  if (t < 128) wvp[128 + t] = pqsh[t] + pqsh[t + 128];
  __syncthreads();
  int u = t & 15, g = t >> 4;
  int a0 = u * 8;
  float4 wv0 = *(float4*)&wvp[a0], wv1 = *(float4*)&wvp[a0 + 4];
  float4 pq0 = *(float4*)&wvp[128 + a0], pq1 = *(float4*)&wvp[128 + a0 + 4];
  float bvv = bv[0];
  int smax = base + 200; if (smax > ml) smax = ml;
#pragma unroll 1
  for (int p = 0; p < 2; p++) {
    int s0 = base + p * 112;
    if (s0 >= smax) break;
    for (int idx = t; idx < 368; idx += 256) {
      int G = idx >> 3, i = idx & 7;
      int s = s0 + G - 15 + 16 * i;
      astT[idx] = (s >= 0 && s < SS) ? ast[b * SS + s] : 0.f;
    }
    __syncthreads();
    float arg[7][8];
#pragma unroll
    for (int i = 0; i < 7; i++) {
      int s = s0 + g + 16 * i;
      if (s < SS) {
        const float* kp = keys + ((size_t)b * SS + s) * AA + a0;
        float4 k0 = *(const float4*)kp, k1 = *(const float4*)(kp + 4);
        arg[i][0] = k0.x + pq0.x; arg[i][1] = k0.y + pq0.y;
        arg[i][2] = k0.z + pq0.z; arg[i][3] = k0.w + pq0.w;
        arg[i][4] = k1.x + pq1.x; arg[i][5] = k1.y + pq1.y;
        arg[i][6] = k1.z + pq1.z; arg[i][7] = k1.w + pq1.w;
      } else {
#pragma unroll
        for (int jj = 0; jj < 8; jj++) arg[i][jj] = 0.f;
      }
    }
    for (int k = 0; k < KK; k++) {
      float4 m0 = *(float4*)&Ml4[k * 132 + a0];
      float4 m1 = *(float4*)&Ml4[k * 132 + a0 + 4];
#pragma unroll
      for (int i = 0; i < 7; i++) {
        float aw = astT[(g + k) * 8 + i];
        arg[i][0] += aw * m0.x; arg[i][1] += aw * m0.y;
        arg[i][2] += aw * m0.z; arg[i][3] += aw * m0.w;
        arg[i][4] += aw * m1.x; arg[i][5] += aw * m1.y;
        arg[i][6] += aw * m1.z; arg[i][7] += aw * m1.w;
      }
    }
#pragma unroll
    for (int i = 0; i < 7; i++) {
      int s = s0 + g + 16 * i;
      float v = ftanh(arg[i][0]) * wv0.x + ftanh(arg[i][1]) * wv0.y
              + ftanh(arg[i][2]) * wv0.z + ftanh(arg[i][3]) * wv0.w
              + ftanh(arg[i][4]) * wv1.x + ftanh(arg[i][5]) * wv1.y
              + ftanh(arg[i][6]) * wv1.z + ftanh(arg[i][7]) * wv1.w;
#pragma unroll
      for (int msk = 1; msk < 16; msk <<= 1) v += __shfl_xor(v, msk);
      if (u == 0 && s < s0 + 112 && s < smax) e[b * SS + s] = v + bvv;
    }
    __syncthreads();
  }
}

// ---------------- softmax + ast + ctx (fully fused) ----------------
__device__ void ctx_phase(int bid, const float* e, const int* mlen,
    const ushort* membf, float* ast, ushort* ctxbf, float* ctxT, char* lds)
{
  float* red  = (float*)lds;        // 8
  float* al   = red + 8;            // 1600
  float* cacc = al + 1600;          // 256
  int b = bid >> 3, dq = bid & 7;
  int ml = mlen[b];
  int t = threadIdx.x;
  const float* er = e + b * SS;
  float m = -3e38f;
  for (int s = t; s < ml; s += 256) m = fmaxf(m, er[s]);
#pragma unroll
  for (int msk = 1; msk < 64; msk <<= 1) m = fmaxf(m, __shfl_xor(m, msk));
  if ((t & 63) == 0) red[t >> 6] = m;
  __syncthreads();
  m = fmaxf(fmaxf(red[0], red[1]), fmaxf(red[2], red[3]));
  __syncthreads();
  float sum = 0.f;
  for (int s = t; s < ml; s += 256) sum += __expf(er[s] - m);
#pragma unroll
  for (int msk = 1; msk < 64; msk <<= 1) sum += __shfl_xor(sum, msk);
  if ((t & 63) == 0) red[t >> 6] = sum;
  __syncthreads();
  float inv = 1.f / (red[0] + red[1] + red[2] + red[3]);
  for (int s = t; s < ml; s += 256) {
    float a_ = __expf(er[s] - m) * inv;
    al[s] = a_;
    if (dq == 0) ast[b * SS + s] += a_;
  }
  __syncthreads();
  int dl = t & 127, half = t >> 7;
  const ushort* mp = membf + (size_t)b * SS * DE + dq * 128 + dl;
  float facc = 0.f;
#pragma unroll 4
  for (int s = half; s < ml; s += 2)
    facc += al[s] * bf2f(mp[(size_t)s * DE]);
  cacc[t] = facc;
  __syncthreads();
  if (t < 128) {
    float v = cacc[t] + cacc[t + 128];
    int d = dq * 128 + t;
    ctxbf[(d >> 8) * 8192 + b * 256 + (d & 255)] = f2bf(v);
    ctxT[d * 32 + b] = v;
  }
}

// ---------------- cls (full-K, fused out + stp partial) ----------------
__device__ void cls_phase(int bid, const float* h1T, const float* ctxT,
    const float* Wcp, const float* bc, const float* Ws,
    float* out, int ts, float* sp_slot, char* lds)
{
  if (bid >= 250) return;
  float* wb = (float*)lds;          // 2*2048
  float* zc = wb + 4096;            // 1024
  int t = threadIdx.x;
  int lane = t & 63;
  int w = __builtin_amdgcn_readfirstlane(t >> 6);
  const float* Wblk = Wcp + (size_t)bid * 8192;
  auto stage = [&](int ch, int buf) {
#pragma unroll
    for (int j = 0; j < 2; j++)
      gload16(Wblk + ch * 2048 + (w * 2 + j) * 256 + lane * 4,
              wb + buf * 2048 + (w * 2 + j) * 256);
  };
  stage(0, 0);
  int b = t & 31, kh = t >> 5;
  float a0 = 0.f, a1 = 0.f, a2 = 0.f, a3 = 0.f;
#pragma unroll 1
  for (int ch = 0; ch < 4; ch++) {
    if (ch < 3) {
      stage(ch + 1, (ch + 1) & 1);
      asm volatile("s_waitcnt vmcnt(2)" ::: "memory");
    } else {
      asm volatile("s_waitcnt vmcnt(0)" ::: "memory");
    }
    __builtin_amdgcn_sched_barrier(0);
    __builtin_amdgcn_s_barrier();
    const float* xb = (ch < 2) ? (h1T + ch * 512 * 32) : (ctxT + (ch - 2) * 512 * 32);
    const float* wc = wb + (ch & 1) * 2048;
#pragma unroll 8
    for (int kk = 0; kk < 64; kk++) {
      int k = kh * 64 + kk;
      float xv = xb[k * 32 + b];
      float4 wv4 = *(const float4*)(wc + k * 4);
      a0 += xv * wv4.x; a1 += xv * wv4.y; a2 += xv * wv4.z; a3 += xv * wv4.w;
    }
    asm volatile("s_waitcnt lgkmcnt(0)" ::: "memory");
    __builtin_amdgcn_sched_barrier(0);
    __builtin_amdgcn_s_barrier();
  }
  *(float4*)&zc[(kh * 32 + b) * 4] = make_float4(a0, a1, a2, a3);
  __syncthreads();
  if (t < 128) {
    int bb = t >> 2, ci = t & 3;
    float v = bc[bid * 4 + ci];
#pragma unroll
    for (int k2 = 0; k2 < 8; k2++) v += zc[(k2 * 32 + bb) * 4 + ci];
    out[(size_t)bb * TT * VV + (size_t)ts * VV + bid * 4 + ci] = v;
    float s = v * Ws[LU + bid * 4 + ci];
    s += __shfl_xor(s, 1);
    s += __shfl_xor(s, 2);
    if (ci == 0) sp_slot[bb * 256 + bid] = s;
  }
}

// ---------------- persistent step loop ----------------
__global__ __launch_bounds__(256) void step_loop(float* ws, float* out,
    const int* __restrict__ mlen, const float* __restrict__ Wq,
    const float* __restrict__ Wv, const float* __restrict__ bv,
    const float* __restrict__ ba, const float* __restrict__ b0,
    const float* __restrict__ b1, const float* __restrict__ bc,
    const float* __restrict__ Ws)
{
  __shared__ char lds[107520];
  const int bid = blockIdx.x;
  float*  keys  = ws + F_KEYS;
  float*  Mv    = ws + F_M;
  ushort* pbf   = (ushort*)(ws + F_PBF);
  ushort* wpa   = (ushort*)(ws + F_WPA);
  ushort* wp0   = (ushort*)(ws + F_WP0);
  ushort* wp1   = (ushort*)(ws + F_WP1);
  float*  wcp   = ws + F_WCP;
  ushort* membf = (ushort*)(ws + F_MEMBF);
  float*  ha32  = ws + F_HA32;
  float*  ca    = ws + F_CA;
  float*  c0p   = ws + F_C0;
  float*  c1p   = ws + F_C1;
  float*  astp  = ws + F_AST;
  ushort* habf  = (ushort*)(ws + F_HABF);
  ushort* h0bf  = (ushort*)(ws + F_H0BF);
  ushort* h1bf  = (ushort*)(ws + F_H1BF);
  ushort* ctxbf = (ushort*)(ws + F_CTXBF);
  float*  ctxT  = ws + F_CTXT;
  float*  h1T   = ws + F_H1T;
  const ushort* zeroc = (const ushort*)(ws + F_ZERO);
  int*    bar   = (int*)(ws + F_BAR);
  float*  hp    = ws + F_HP;
  float*  sp    = ws + F_SP;
  float*  ebuf  = ws + F_E;
  int* cnt = bar;
  int* sense = bar + 32;
  int ep = 0;
  int par = 0;
#pragma unroll 1
  for (int ts = 0; ts < TT; ts++) {
    ushort* habf_r = habf + par * 32768;
    ushort* habf_w = habf + (par ^ 1) * 32768;
    ushort* h0bf_r = h0bf + par * 32768;
    ushort* h0bf_w = h0bf + (par ^ 1) * 32768;
    ushort* h1bf_r = h1bf + par * 32768;
    ushort* h1bf_w = h1bf + (par ^ 1) * 32768;
    {
      XSeg xs = { pbf + (size_t)ts * 8192, 1, ctxbf, 4, habf_r, 4, zeroc };
      gemm_gates(bid, xs, wpa, 5, ba, ca, ha32, habf_w, nullptr, nullptr, nullptr, lds);
    }
    gbar(cnt, sense, ++ep);
    energy_phase(bid, keys, ha32, Mv, astp, Wq, Wv, bv, mlen, ebuf, lds);
    gbar(cnt, sense, ++ep);
    ctx_phase(bid, ebuf, mlen, membf, astp, ctxbf, ctxT, lds);
    gbar(cnt, sense, ++ep);
    {
      XSeg xs = { habf_w, 4, ctxbf, 4, h0bf_r, 4, zeroc };
      gemm_gates(bid, xs, wp0, 6, b0, c0p, nullptr, h0bf_w, nullptr, nullptr, nullptr, lds);
    }
    gbar(cnt, sense, ++ep);
    {
      XSeg xs = { h0bf_w, 4, h1bf_r, 4, nullptr, 0, zeroc };
      gemm_gates(bid, xs, wp1, 4, b1, c1p, nullptr, h1bf_w, h1T,
                 hp + (size_t)ts * 8192, Ws, lds);
    }
    gbar(cnt, sense, ++ep);
    cls_phase(bid, h1T, ctxT, wcp, bc, Ws, out, ts, sp + (size_t)ts * 8192, lds);
    par ^= 1;
  }
}

// ---------------- stp finalize ----------------
__global__ __launch_bounds__(256) void final_stp(const float* __restrict__ hp,
    const float* __restrict__ sp, const float* __restrict__ bs, float* __restrict__ out)
{
  int idx = blockIdx.x * 256 + threadIdx.x;
  if (idx < TT * BB) {
    int ts = idx >> 5, b = idx & 31;
    float s = bs[0];
    const float* h = hp + (size_t)ts * 8192 + b * 256;
    const float* p = sp + (size_t)ts * 8192 + b * 256;
    for (int i = 0; i < 256; i++) s += h[i];
    for (int i = 0; i < 250; i++) s += p[i];
    out[(size_t)BB * TT * VV + (size_t)b * TT + ts] = s;
  }
}

// ---------------- launcher ----------------

extern "C" void kernel_launch(void* const* d_in, const int* in_sizes, int n_in,
                              void* d_out, int out_size, void* d_ws, size_t ws_size,
                              hipStream_t stream)
{
  const int*   tokens = (const int*)  d_in[0];
  const float* memory = (const float*)d_in[1];
  const int*   mlen   = (const int*)  d_in[2];
  const float* emb    = (const float*)d_in[3];
  const float* Wp1    = (const float*)d_in[4];
  const float* bp1    = (const float*)d_in[5];
  const float* Wp2    = (const float*)d_in[6];
  const float* bp2    = (const float*)d_in[7];
  const float* Wq     = (const float*)d_in[8];
  const float* Wmem   = (const float*)d_in[9];
  const float* convk  = (const float*)d_in[10];
  const float* Wloc   = (const float*)d_in[11];
  const float* Wv     = (const float*)d_in[12];
  const float* bv     = (const float*)d_in[13];
  const float* Wa     = (const float*)d_in[14];
  const float* Ua     = (const float*)d_in[15];
  const float* ba     = (const float*)d_in[16];
  const float* W0     = (const float*)d_in[17];
  const float* U0     = (const float*)d_in[18];
  const float* b0     = (const float*)d_in[19];
  const float* W1     = (const float*)d_in[20];
  const float* U1     = (const float*)d_in[21];
  const float* b1     = (const float*)d_in[22];
  const float* Wc     = (const float*)d_in[23];
  const float* bc     = (const float*)d_in[24];
  const float* Ws     = (const float*)d_in[25];
  const float* bs     = (const float*)d_in[26];
  float* out = (float*)d_out;
  float* ws = (float*)d_ws;

  // zero state block (includes zero-chunk and barrier counters)
  hipMemsetAsync(ws + F_ST, 0, (F_STEND - F_ST) * sizeof(float), stream);

  conv_mem<<<(BB * SS * DE / 4 + 255) / 256, 256, 0, stream>>>(
      memory, (ushort*)(ws + F_MEMBF), BB * SS * DE / 4);
  pack_lstm<<<2560, 256, 0, stream>>>(Wa, Ua, PR + DE, 2304, (ushort*)(ws + F_WPA), 5);
  pack_lstm<<<3072, 256, 0, stream>>>(W0, U0, LU + DE, 3072, (ushort*)(ws + F_WP0), 6);
  pack_lstm<<<2048, 256, 0, stream>>>(W1, U1, LU, 2048, (ushort*)(ws + F_WP1), 4);
  pack_wc<<<2048, 256, 0, stream>>>(Wc, ws + F_WCP);
  keys_kernel<<<dim3(200, BB), 256, 0, stream>>>(memory, Wmem, ws + F_KEYS);
  mconv_kernel<<<KK, AA, 0, stream>>>(convk, Wloc, ws + F_M);
  prenet_all<<<dim3(TT, 2), 256, 0, stream>>>(tokens, emb, Wp1, bp1, Wp2, bp2,
                                              (ushort*)(ws + F_PBF));

  step_loop<<<256, 256, 0, stream>>>(ws, out, mlen, Wq, Wv, bv, ba, b0, b1, bc, Ws);

  final_stp<<<32, 256, 0, stream>>>(ws + F_HP, ws + F_SP, bs, out);
}